// Round 5
// baseline (279.110 us; speedup 1.0000x reference)
//
#include <hip/hip_runtime.h>
#include <math.h>

// Problem constants (B=2, S=2048 -> N=4096 tokens)
#define NTOK 4096
#define DDIM 512
#define HDIM 2048
#define NEXP 16

// A-side fragment-tiled layouts (xa, hb): elem(t, row, k) =
//   ((row>>4)*RB + (k>>3)*128 + (row&15)*8 + (k&7)), staged linearly into LDS
// via global_load_lds. B-side (weights) is staged DIRECTLY from fp32 W with an
// in-register bf16 convert + k-pair pack into padded LDS [128 n][17 u32]
// (17 odd -> conflict-free fragment reads; no separate transpose pass).
// [R4 post-mortem: the standalone W-transpose cost ~260 MB HBM round trip
// (read fp32, write bf16, re-read bf16) and its blocks carried the GEMM's
// 48 KB LDS allocation. Folding it into the K-loop removes both.]
// K-loop: counted s_waitcnt vmcnt(2) + raw barrier; B-regs depth-1 and A
// gld16 depth-2 stay in flight across every barrier; drains only at the tail.

// Workspace layout (bytes). counts padded: one counter per 64 B line.
#define WS_COUNTS    0u            // 16 lines x 64 B = 1 KB
#define WS_OFFSETS   1024u
#define WS_NTILES    1280u
#define WS_TM        1536u         // <=80 ints
#define WS_EPOS      4096u         // NTOK*2 ints (32 KB)
#define WS_TOK       36864u        // NEXP*NTOK ints (256 KB)
#define WS_WL        299008u       // NEXP*NTOK floats (256 KB)
#define WS_XA        1048576u      // tiled A for gemm1: 80*128*512 bf16 = 10.5 MB
#define WS_YB        11534336u     // ybuf [4][8192][512] bf16 = 33.55 MB
#define WS_HB        78643200u     // tiled [t80][sub8][c256][16][8] bf16 = 41.9 MB

typedef __attribute__((ext_vector_type(8))) short short8;
typedef __attribute__((ext_vector_type(4))) float floatx4;
typedef unsigned short ushort_t;

__device__ __forceinline__ ushort_t f2bf(float f) {
    unsigned u = __float_as_uint(f);
    u += 0x7fffu + ((u >> 16) & 1u);   // round-to-nearest-even
    return (ushort_t)(u >> 16);
}
__device__ __forceinline__ float bf2f(ushort_t u) {
    return __uint_as_float((unsigned)u << 16);
}
__device__ __forceinline__ unsigned pk2(float a, float b) {
    return (unsigned)f2bf(a) | ((unsigned)f2bf(b) << 16);
}

// async global->LDS, 16 B per lane: dst is wave-uniform base (+lane*16 in HW),
// src is per-lane.
__device__ __forceinline__ void gld16(const void* g, void* l) {
    __builtin_amdgcn_global_load_lds(
        (const __attribute__((address_space(1))) unsigned*)g,
        (__attribute__((address_space(3))) unsigned*)l, 16, 0, 0);
}

#define WAIT2()  asm volatile("s_waitcnt vmcnt(2)" ::: "memory")
#define WAIT0()  asm volatile("s_waitcnt vmcnt(0)" ::: "memory")
#define LGKM_BAR() asm volatile("s_waitcnt lgkmcnt(0)\n\ts_barrier" ::: "memory")

union U8 { unsigned u[4]; short8 s; };

// ---------------- gating: 512 blocks x 8 tokens ----------------------------
__global__ __launch_bounds__(256) void gating_kernel(
    const float* __restrict__ x, const float* __restrict__ Wg,
    const float* __restrict__ bg, int* __restrict__ counts,
    int* __restrict__ tok_list, float* __restrict__ w_list,
    int* __restrict__ epos)
{
    __shared__ __align__(16) float smem[4416];
    __shared__ int lcnt[16], lbase[16];
    const int tid = threadIdx.x;
    const int bid = blockIdx.x;

    float (*xs)[520] = (float(*)[520])smem;
    float (*lsm)[16][2] = (float(*)[16][2])(smem + 4160);
    const int t0 = bid * 8;
    const float* xg = x + (size_t)t0 * DDIM;
    #pragma unroll
    for (int p = 0; p < 4; ++p) {
        const int idx = p * 1024 + tid * 4;
        *(float4*)&xs[idx >> 9][idx & 511] = *(const float4*)(xg + idx);
    }
    if (tid < 16) lcnt[tid] = 0;
    __syncthreads();
    const int tl = tid >> 5, e = (tid >> 1) & 15, h = tid & 1;
    float a0 = 0.f, a1 = 0.f, a2 = 0.f, a3 = 0.f;
    #pragma unroll 8
    for (int it = 0; it < 64; ++it) {
        const int d = h * 256 + it * 4;
        const float4 xv = *(const float4*)&xs[tl][d];
        a0 = fmaf(xv.x, Wg[(d + 0) * 16 + e], a0);
        a1 = fmaf(xv.y, Wg[(d + 1) * 16 + e], a1);
        a2 = fmaf(xv.z, Wg[(d + 2) * 16 + e], a2);
        a3 = fmaf(xv.w, Wg[(d + 3) * 16 + e], a3);
    }
    lsm[tl][e][h] = (a0 + a1) + (a2 + a3);
    __syncthreads();

    int i0 = 0, i1 = -1, r0 = 0, r1 = 0;
    float w0 = 0.f, w1 = 0.f;
    const bool tokth = ((tid & 31) == 0);
    if (tokth) {
        float l[16];
        #pragma unroll
        for (int j = 0; j < NEXP; ++j) l[j] = lsm[tl][j][0] + lsm[tl][j][1] + bg[j];
        float m = -1e30f;
        #pragma unroll
        for (int j = 0; j < NEXP; ++j) m = fmaxf(m, l[j]);
        float s = 0.f;
        #pragma unroll
        for (int j = 0; j < NEXP; ++j) s += __expf(l[j] - m);
        float v0 = -1e30f;
        #pragma unroll
        for (int j = 0; j < NEXP; ++j)
            if (l[j] > v0) { v0 = l[j]; i0 = j; }
        float v1 = -1e30f;
        #pragma unroll
        for (int j = 0; j < NEXP; ++j)
            if (j != i0 && l[j] > v1) { v1 = l[j]; i1 = j; }
        w0 = __expf(v0 - m) / s;
        w1 = __expf(v1 - m) / s;
        r0 = atomicAdd(&lcnt[i0], 1);      // LDS atomics: local rank
        r1 = atomicAdd(&lcnt[i1], 1);
    }
    __syncthreads();
    if (tid < 16 && lcnt[tid] > 0)
        lbase[tid] = atomicAdd(&counts[tid * 16], lcnt[tid]);
    __syncthreads();
    if (tokth) {
        const int t = t0 + tl;
        const int p0 = lbase[i0] + r0;
        tok_list[i0 * NTOK + p0] = t;
        w_list[i0 * NTOK + p0] = w0;
        epos[t * 2 + 0] = (i0 << 16) | p0;
        const int p1 = lbase[i1] + r1;
        tok_list[i1 * NTOK + p1] = t;
        w_list[i1 * NTOK + p1] = w1;
        epos[t * 2 + 1] = (i1 << 16) | p1;
    }
}

// offsets prefix-scan + 128-row tile list, wave-parallel (padded counts)
__global__ void scan_kernel(const int* __restrict__ counts, int* __restrict__ offsets,
                            int* __restrict__ tm, int* __restrict__ ntiles)
{
    const int lane = threadIdx.x;
    int c = (lane < NEXP) ? counts[lane * 16] : 0;
    int t = (c + 127) >> 7;
    int ic = c, it = t;
    #pragma unroll
    for (int off = 1; off < 16; off <<= 1) {
        const int pc = __shfl_up(ic, off, 64);
        const int pt = __shfl_up(it, off, 64);
        if (lane >= off) { ic += pc; it += pt; }
    }
    if (lane < NEXP) {
        offsets[lane] = ic - c;
        if (lane == NEXP - 1) { offsets[NEXP] = ic; ntiles[0] = it; }
        const int tb = it - t;
        for (int i = 0; i < t; ++i) tm[tb + i] = (lane << 16) | i;
    }
}

// gather x rows (fp32) into fragment-tiled bf16 A, slot order per 128-tile.
__global__ __launch_bounds__(256) void gather_xa(
    const float* __restrict__ x, const int* __restrict__ tok_list,
    const int* __restrict__ counts, const int* __restrict__ tm,
    const int* __restrict__ ntiles, ushort_t* __restrict__ xa)
{
    const int b = blockIdx.x;
    if (b >= ntiles[0]) return;
    const int info = tm[b];
    const int e = info >> 16, m0 = (info & 0xffff) << 7;
    const int Me = counts[e * 16];
    const int row = threadIdx.x >> 1;
    const int half = threadIdx.x & 1;
    const int kbase = blockIdx.y * 128 + half * 64;
    const int tok = tok_list[e * NTOK + min(m0 + row, Me - 1)];
    const float* src = x + (size_t)tok * DDIM + kbase;
    ushort_t* dstb = xa + (size_t)b * 65536 + (size_t)(row >> 4) * 8192 + (row & 15) * 8;
    #pragma unroll
    for (int q = 0; q < 16; ++q) {
        const int k = kbase + q * 4;
        const float4 v = *(const float4*)(src + q * 4);
        ushort4 o = make_ushort4(f2bf(v.x), f2bf(v.y), f2bf(v.z), f2bf(v.w));
        *(ushort4*)(dstb + (size_t)(k >> 3) * 128 + (k & 7)) = o;
    }
}

// ---- GEMM1: A via gld16 3-buffer; B = W1 fp32 staged+transposed in-loop ----
// LDS: A 3x8 KB (linear frag layout) + B 2x[128 n][17 u32] = 41 KB.
__global__ __launch_bounds__(256, 3) void gemm1_mfma(
    const ushort_t* __restrict__ xa, const float* __restrict__ W1,
    const float* __restrict__ b1, const int* __restrict__ tm,
    const int* __restrict__ ntiles, ushort_t* __restrict__ hb)
{
    const int bid = blockIdx.x;
    // XCD-bijective swizzle (1280 = 8*160): same-t/same-e neighbors colocate.
    const int swz = (bid & 7) * 160 + (bid >> 3);
    const int t = swz >> 4;
    if (t >= ntiles[0]) return;
    const int e = tm[t] >> 16;
    const int n0 = (swz & 15) << 7;
    const int tid = threadIdx.x, lane = tid & 63, w = tid >> 6;
    const int fm = lane & 15, fq = lane >> 4;
    const int wr = (w >> 1) << 6, wc = (w & 1) << 6;

    __shared__ __align__(16) ushort_t lds[20992];   // 41984 B
    ushort_t* Al = lds;                              // 3 x 4096 ushorts
    unsigned* Bb = (unsigned*)(lds + 12288);         // 2 x 2176 u32

    const ushort_t* gA = xa + (size_t)t * 65536 + lane * 8;
    const int s0 = w, s1 = w + 4;
    const float* gB = W1 + (size_t)e * (DDIM * HDIM) + n0;
    const int qa = tid >> 5, ca4 = (tid & 31) << 2;  // unit: (kpair qa / qa+8, 4n)

    float4 bvv[4];

    #define AGLD(k) do {                                                    \
        ushort_t* ab_ = Al + ((k) % 3) * 4096;                              \
        gld16(gA + (size_t)s0 * 8192 + (k) * 512, ab_ + s0 * 512);          \
        gld16(gA + (size_t)s1 * 8192 + (k) * 512, ab_ + s1 * 512);          \
    } while (0)

    #define BLOAD(k) do {                                                   \
        const float* r0_ = gB + (size_t)((k) * 32 + 2 * qa) * HDIM + ca4;   \
        const float* r1_ = gB + (size_t)((k) * 32 + 2 * qa + 16) * HDIM + ca4; \
        bvv[0] = *(const float4*)r0_;                                       \
        bvv[1] = *(const float4*)(r0_ + HDIM);                              \
        bvv[2] = *(const float4*)r1_;                                       \
        bvv[3] = *(const float4*)(r1_ + HDIM);                              \
    } while (0)

    #define BWRITE(k) do {                                                  \
        unsigned* BL_ = Bb + ((k) & 1) * 2176;                              \
        BL_[(ca4 + 0) * 17 + qa] = pk2(bvv[0].x, bvv[1].x);                 \
        BL_[(ca4 + 1) * 17 + qa] = pk2(bvv[0].y, bvv[1].y);                 \
        BL_[(ca4 + 2) * 17 + qa] = pk2(bvv[0].z, bvv[1].z);                 \
        BL_[(ca4 + 3) * 17 + qa] = pk2(bvv[0].w, bvv[1].w);                 \
        BL_[(ca4 + 0) * 17 + qa + 8] = pk2(bvv[2].x, bvv[3].x);             \
        BL_[(ca4 + 1) * 17 + qa + 8] = pk2(bvv[2].y, bvv[3].y);             \
        BL_[(ca4 + 2) * 17 + qa + 8] = pk2(bvv[2].z, bvv[3].z);             \
        BL_[(ca4 + 3) * 17 + qa + 8] = pk2(bvv[2].w, bvv[3].w);             \
    } while (0)

    #define COMPUTE(k) do {                                                 \
        const ushort_t* la_ = Al + ((k) % 3) * 4096 + ((w >> 1) * 4) * 512 + lane * 8; \
        const unsigned* bb_ = Bb + ((k) & 1) * 2176                         \
                            + ((w & 1) * 64 + (lane & 15)) * 17 + (lane >> 4) * 4; \
        short8 af[4];                                                       \
        _Pragma("unroll")                                                   \
        for (int i = 0; i < 4; ++i) af[i] = *(const short8*)(la_ + i * 512);\
        _Pragma("unroll")                                                   \
        for (int j = 0; j < 4; ++j) {                                       \
            U8 tb_;                                                         \
            tb_.u[0] = bb_[j * 272 + 0]; tb_.u[1] = bb_[j * 272 + 1];       \
            tb_.u[2] = bb_[j * 272 + 2]; tb_.u[3] = bb_[j * 272 + 3];       \
            const short8 bf_ = tb_.s;                                       \
            _Pragma("unroll")                                               \
            for (int i = 0; i < 4; ++i)                                     \
                acc[i][j] = __builtin_amdgcn_mfma_f32_16x16x32_bf16(        \
                    af[i], bf_, acc[i][j], 0, 0, 0);                        \
        }                                                                   \
    } while (0)

    #define STEP(k, WM) do {                                                \
        WM();                       /* B(k) regs + A(k) lds landed */       \
        BWRITE(k);                                                          \
        LGKM_BAR();                                                         \
        if ((k) < 15) BLOAD((k) + 1);                                       \
        if ((k) < 14) AGLD((k) + 2);                                        \
        COMPUTE(k);                                                         \
    } while (0)

    // prologue: queue = [B0(4), A0(2), A1(2)]
    BLOAD(0);
    AGLD(0);
    AGLD(1);

    floatx4 acc[4][4] = {};
    #pragma unroll 1
    for (int kc = 0; kc < 14; kc += 2) {
        STEP(kc, WAIT2);
        STEP(kc + 1, WAIT2);
    }
    STEP(14, WAIT2);
    STEP(15, WAIT0);
    __syncthreads();
    #undef AGLD
    #undef BLOAD
    #undef BWRITE
    #undef COMPUTE
    #undef STEP

    ushort_t* ls = lds;            // epilogue scratch (32 KB of 41)
    #pragma unroll
    for (int j = 0; j < 4; ++j) {
        const float bias = b1[(size_t)e * HDIM + n0 + wc + j * 16 + fm];
        #pragma unroll
        for (int i = 0; i < 4; ++i)
            #pragma unroll
            for (int r = 0; r < 4; ++r) {
                const int row = wr + i * 16 + fq * 4 + r;
                ls[row * 128 + wc + j * 16 + fm] =
                    f2bf(fmaxf(acc[i][j][r] + bias, 0.f));
            }
    }
    __syncthreads();
    ushort_t* hbase = hb + (size_t)t * 262144 + (size_t)(n0 >> 3) * 128;
    #pragma unroll
    for (int p = 0; p < 8; ++p) {
        const int unit = tid + p * 256;
        const int row = unit >> 4, c16 = unit & 15;
        *(short8*)(hbase + (size_t)(row >> 4) * 32768 + (size_t)c16 * 128
                   + (row & 15) * 8) = *(const short8*)&ls[row * 128 + c16 * 8];
    }
}

// ---- GEMM2: same structure; B = W2 fp32 in-loop; split-K=4 to ybuf --------
__global__ __launch_bounds__(256, 3) void gemm2_mfma(
    const ushort_t* __restrict__ hb, const float* __restrict__ W2,
    const float* __restrict__ b2, const float* __restrict__ w_list,
    const int* __restrict__ counts, const int* __restrict__ offsets,
    const int* __restrict__ tm, const int* __restrict__ ntiles,
    ushort_t* __restrict__ yb)
{
    const int bid = blockIdx.x;
    const int swz = (bid & 7) * 160 + (bid >> 3);
    const int n0i = swz & 3;
    const int q_ = swz >> 2;           // 0..319
    const int kz = q_ / 80;
    const int t = q_ - kz * 80;
    if (t >= ntiles[0]) return;
    const int info = tm[t];
    const int e = info >> 16, m0 = (info & 0xffff) << 7;
    const int Me = counts[e * 16], aoff = offsets[e];
    const int n0 = n0i << 7;
    const int tid = threadIdx.x, lane = tid & 63, w = tid >> 6;
    const int fm = lane & 15, fq = lane >> 4;
    const int wr = (w >> 1) << 6, wc = (w & 1) << 6;

    __shared__ __align__(16) ushort_t lds[20992];
    ushort_t* Al = lds;
    unsigned* Bb = (unsigned*)(lds + 12288);

    const ushort_t* gA = hb + (size_t)t * 262144 + (size_t)kz * 8192 + lane * 8;
    const int s0 = w, s1 = w + 4;
    const float* gB = W2 + (size_t)e * (DDIM * HDIM) + (size_t)kz * 512 * DDIM + n0;
    const int qa = tid >> 5, ca4 = (tid & 31) << 2;

    float4 bvv[4];

    #define AGLD(k) do {                                                    \
        ushort_t* ab_ = Al + ((k) % 3) * 4096;                              \
        gld16(gA + (size_t)s0 * 32768 + (k) * 512, ab_ + s0 * 512);         \
        gld16(gA + (size_t)s1 * 32768 + (k) * 512, ab_ + s1 * 512);         \
    } while (0)

    #define BLOAD(k) do {                                                   \
        const float* r0_ = gB + (size_t)((k) * 32 + 2 * qa) * DDIM + ca4;   \
        const float* r1_ = gB + (size_t)((k) * 32 + 2 * qa + 16) * DDIM + ca4; \
        bvv[0] = *(const float4*)r0_;                                       \
        bvv[1] = *(const float4*)(r0_ + DDIM);                              \
        bvv[2] = *(const float4*)r1_;                                       \
        bvv[3] = *(const float4*)(r1_ + DDIM);                              \
    } while (0)

    #define BWRITE(k) do {                                                  \
        unsigned* BL_ = Bb + ((k) & 1) * 2176;                              \
        BL_[(ca4 + 0) * 17 + qa] = pk2(bvv[0].x, bvv[1].x);                 \
        BL_[(ca4 + 1) * 17 + qa] = pk2(bvv[0].y, bvv[1].y);                 \
        BL_[(ca4 + 2) * 17 + qa] = pk2(bvv[0].z, bvv[1].z);                 \
        BL_[(ca4 + 3) * 17 + qa] = pk2(bvv[0].w, bvv[1].w);                 \
        BL_[(ca4 + 0) * 17 + qa + 8] = pk2(bvv[2].x, bvv[3].x);             \
        BL_[(ca4 + 1) * 17 + qa + 8] = pk2(bvv[2].y, bvv[3].y);             \
        BL_[(ca4 + 2) * 17 + qa + 8] = pk2(bvv[2].z, bvv[3].z);             \
        BL_[(ca4 + 3) * 17 + qa + 8] = pk2(bvv[2].w, bvv[3].w);             \
    } while (0)

    #define COMPUTE(k) do {                                                 \
        const ushort_t* la_ = Al + ((k) % 3) * 4096 + ((w >> 1) * 4) * 512 + lane * 8; \
        const unsigned* bb_ = Bb + ((k) & 1) * 2176                         \
                            + ((w & 1) * 64 + (lane & 15)) * 17 + (lane >> 4) * 4; \
        short8 af[4];                                                       \
        _Pragma("unroll")                                                   \
        for (int i = 0; i < 4; ++i) af[i] = *(const short8*)(la_ + i * 512);\
        _Pragma("unroll")                                                   \
        for (int j = 0; j < 4; ++j) {                                       \
            U8 tb_;                                                         \
            tb_.u[0] = bb_[j * 272 + 0]; tb_.u[1] = bb_[j * 272 + 1];       \
            tb_.u[2] = bb_[j * 272 + 2]; tb_.u[3] = bb_[j * 272 + 3];       \
            const short8 bf_ = tb_.s;                                       \
            _Pragma("unroll")                                               \
            for (int i = 0; i < 4; ++i)                                     \
                acc[i][j] = __builtin_amdgcn_mfma_f32_16x16x32_bf16(        \
                    af[i], bf_, acc[i][j], 0, 0, 0);                        \
        }                                                                   \
    } while (0)

    #define STEP(k, WM) do {                                                \
        WM();                                                               \
        BWRITE(k);                                                          \
        LGKM_BAR();                                                         \
        if ((k) < 15) BLOAD((k) + 1);                                       \
        if ((k) < 14) AGLD((k) + 2);                                        \
        COMPUTE(k);                                                         \
    } while (0)

    BLOAD(0);
    AGLD(0);
    AGLD(1);

    floatx4 acc[4][4] = {};
    #pragma unroll 1
    for (int kc = 0; kc < 14; kc += 2) {
        STEP(kc, WAIT2);
        STEP(kc + 1, WAIT2);
    }
    STEP(14, WAIT2);
    STEP(15, WAIT0);
    __syncthreads();
    #undef AGLD
    #undef BLOAD
    #undef BWRITE
    #undef COMPUTE
    #undef STEP

    ushort_t* ls = lds;
    #pragma unroll
    for (int j = 0; j < 4; ++j) {
        const float bias = (kz == 0) ? b2[(size_t)e * DDIM + n0 + wc + j * 16 + fm] : 0.f;
        #pragma unroll
        for (int i = 0; i < 4; ++i)
            #pragma unroll
            for (int r = 0; r < 4; ++r) {
                const int row = wr + i * 16 + fq * 4 + r;
                const float gw = w_list[e * NTOK + min(m0 + row, Me - 1)];
                ls[row * 128 + wc + j * 16 + fm] = f2bf(gw * (acc[i][j][r] + bias));
            }
    }
    __syncthreads();
    ushort_t* ybase = yb + (size_t)kz * (8192 * 512) + n0;
    #pragma unroll
    for (int p = 0; p < 8; ++p) {
        const int unit = tid + p * 256;
        const int row = unit >> 4, c16 = unit & 15;
        if (m0 + row < Me)
            *(short8*)(ybase + (size_t)(aoff + m0 + row) * 512 + c16 * 8)
                = *(const short8*)&ls[row * 128 + c16 * 8];
    }
}

// out = LayerNorm(x + sum_{kz=0..3} (y[kz][r0] + y[kz][r1])) * gamma + beta
__global__ __launch_bounds__(256) void ln_kernel(
    const float* __restrict__ x, const ushort_t* __restrict__ yb,
    const int* __restrict__ epos, const int* __restrict__ offsets,
    const float* __restrict__ gamma, const float* __restrict__ beta,
    float* __restrict__ out)
{
    const int t = blockIdx.x * 4 + (threadIdx.x >> 6);
    const int lane = threadIdx.x & 63;
    const int d0 = lane * 8;

    const int p0 = epos[2 * t + 0];
    const int p1 = epos[2 * t + 1];
    const size_t r0 = (size_t)(offsets[p0 >> 16] + (p0 & 0xFFFF));
    const size_t r1 = (size_t)(offsets[p1 >> 16] + (p1 & 0xFFFF));

    short8 ys[8];
    #pragma unroll
    for (int kz = 0; kz < 4; ++kz) {
        ys[kz * 2 + 0] = *(const short8*)(yb + (size_t)kz * (8192 * 512) + r0 * 512 + d0);
        ys[kz * 2 + 1] = *(const short8*)(yb + (size_t)kz * (8192 * 512) + r1 * 512 + d0);
    }
    float xv[8];
    *(float4*)&xv[0] = *(const float4*)(x + (size_t)t * DDIM + d0);
    *(float4*)&xv[4] = *(const float4*)(x + (size_t)t * DDIM + d0 + 4);

    float v[8];
    float s = 0.f;
    #pragma unroll
    for (int i = 0; i < 8; ++i) {
        float a = xv[i];
        #pragma unroll
        for (int q = 0; q < 8; ++q) a += bf2f((ushort_t)ys[q][i]);
        v[i] = a;
        s += a;
    }
    #pragma unroll
    for (int o = 32; o > 0; o >>= 1) s += __shfl_xor(s, o, 64);
    const float mu = s * (1.f / DDIM);
    float q = 0.f;
    #pragma unroll
    for (int i = 0; i < 8; ++i) { const float d_ = v[i] - mu; q = fmaf(d_, d_, q); }
    #pragma unroll
    for (int o = 32; o > 0; o >>= 1) q += __shfl_xor(q, o, 64);
    const float rstd = rsqrtf(q * (1.f / DDIM) + 1e-5f);

    float g[8], bt[8], o8[8];
    *(float4*)&g[0] = *(const float4*)(gamma + d0);
    *(float4*)&g[4] = *(const float4*)(gamma + d0 + 4);
    *(float4*)&bt[0] = *(const float4*)(beta + d0);
    *(float4*)&bt[4] = *(const float4*)(beta + d0 + 4);
    #pragma unroll
    for (int i = 0; i < 8; ++i) o8[i] = (v[i] - mu) * rstd * g[i] + bt[i];
    *(float4*)(out + (size_t)t * DDIM + d0) = *(float4*)&o8[0];
    *(float4*)(out + (size_t)t * DDIM + d0 + 4) = *(float4*)&o8[4];
}

extern "C" void kernel_launch(void* const* d_in, const int* in_sizes, int n_in,
                              void* d_out, int out_size, void* d_ws, size_t ws_size,
                              hipStream_t stream) {
    const float* x     = (const float*)d_in[0];
    const float* Wg    = (const float*)d_in[1];
    const float* bg    = (const float*)d_in[2];
    const float* W1    = (const float*)d_in[3];
    const float* b1    = (const float*)d_in[4];
    const float* W2    = (const float*)d_in[5];
    const float* b2    = (const float*)d_in[6];
    const float* gamma = (const float*)d_in[7];
    const float* beta  = (const float*)d_in[8];
    float* out = (float*)d_out;

    char* ws = (char*)d_ws;
    int*      counts   = (int*)(ws + WS_COUNTS);
    int*      offsets  = (int*)(ws + WS_OFFSETS);
    int*      ntiles   = (int*)(ws + WS_NTILES);
    int*      tm       = (int*)(ws + WS_TM);
    int*      epos     = (int*)(ws + WS_EPOS);
    int*      tok_list = (int*)(ws + WS_TOK);
    float*    w_list   = (float*)(ws + WS_WL);
    ushort_t* xa       = (ushort_t*)(ws + WS_XA);
    ushort_t* yb       = (ushort_t*)(ws + WS_YB);
    ushort_t* hb       = (ushort_t*)(ws + WS_HB);

    hipMemsetAsync(counts, 0, 1024, stream);
    gating_kernel<<<512, 256, 0, stream>>>(x, Wg, bg, counts, tok_list, w_list, epos);
    scan_kernel<<<1, 64, 0, stream>>>(counts, offsets, tm, ntiles);
    gather_xa<<<dim3(80, 4), 256, 0, stream>>>(x, tok_list, counts, tm, ntiles, xa);
    gemm1_mfma<<<1280, 256, 0, stream>>>(xa, W1, b1, tm, ntiles, hb);
    gemm2_mfma<<<1280, 256, 0, stream>>>(hb, W2, b2, w_list, counts, offsets,
                                         tm, ntiles, yb);
    ln_kernel<<<NTOK / 4, 256, 0, stream>>>(x, yb, epos, offsets, gamma, beta, out);
}